// Round 3
// baseline (148.061 us; speedup 1.0000x reference)
//
#include <hip/hip_runtime.h>
#include <cstdint>
#include <cstddef>

// Problem constants: B=2, N=16384, K=32, F=64, E=16
#define LOGN 14

typedef __bf16 bf16x8 __attribute__((ext_vector_type(8)));
typedef float f32x4 __attribute__((ext_vector_type(4)));
typedef unsigned u32;

// raw barrier + lgkmcnt(0)-only wait (vmcnt/expcnt unconstrained: 0xC07F)
#define BARRIER() __builtin_amdgcn_s_barrier()
#define LGKM0()   __builtin_amdgcn_s_waitcnt(0xC07F)
// full scheduling fence: nothing moves across (pins the SW pipeline)
#define SFENCE()  __builtin_amdgcn_sched_barrier(0)

__device__ __forceinline__ u32 fbits(float f) { return __builtin_bit_cast(u32, f); }
// pack two f32 -> dword of 2 bf16 (RNE), lo -> low16
__device__ __forceinline__ u32 pkrne(float lo, float hi) {
  u32 a = fbits(lo); a = a + 0x7fffu + ((a >> 16) & 1u);
  u32 b = fbits(hi); b = b + 0x7fffu + ((b >> 16) & 1u);
  return (b & 0xffff0000u) | (a >> 16);
}

// ----------------------------------------------------------------------------
// k-enumeration (R9): k in [0,1024) <-> (L,n) via chunk ch = k>>3, wv = k&7:
//   t = ch>>4, c = ch&15, L = 4*c + (t>>1), n = 8*(t&1) + wv.
// Chosen so that phase A's G-write has lane-c in the LOW bits of the chunk
// index (bank spread), and so that the B-frag S value for (lane c, l-tile lt)
// is element lt of the contiguous float4 S_row[4c..4c+3] -> S rows gather as
// one dwordx4 per quadrant instead of 4 strided dwords. Phase B reads k
// linearly (ch = 4s+q) and wt is pre-permuted to match.
// ----------------------------------------------------------------------------

// wt[m][k] = w[L(k)][m][n(k)]/32 (bf16), 64x1024 = 128KB
__global__ void prep_wt(const float* __restrict__ w, unsigned short* __restrict__ wt) {
  int idx = blockIdx.x * 256 + threadIdx.x;
  int m = idx >> 10, k = idx & 1023;
  int ch = k >> 3, wv = k & 7, t = ch >> 4, cc = ch & 15;
  int l = (cc << 2) + (t >> 1), n = ((t & 1) << 3) + wv;
  u32 u = fbits(w[l * 1024 + m * 16 + n] * 0.03125f);
  wt[idx] = (unsigned short)((u + 0x7fffu + ((u >> 16) & 1u)) >> 16);
}

__device__ __forceinline__ bf16x8 mk_bw(const float* wp) {
  float v[8];
  #pragma unroll
  for (int i = 0; i < 8; ++i) v[i] = wp[i] * 0.03125f;
  uint4 pk{pkrne(v[0], v[1]), pkrne(v[2], v[3]), pkrne(v[4], v[5]), pkrne(v[6], v[7])};
  return __builtin_bit_cast(bf16x8, pk);
}

// ============================================================================
// WG = 256 threads (4 waves) = 16 nodes; wave wid owns nodes wid*4..wid*4+3
// end-to-end in phase A — NO barriers. Per node, fragments gathered directly
// from global:
//   A-frag lane(q,c) reg i = E[j=q*8+i][n=c]          (4x64B segs/instr)
//   B-frag lane(q,c) tile lt reg i = S[j=q*8+i][L=4c+lt]
//     = element lt of dwordx4 at S_row[4c..4c+3]      (4x256B segs/instr)
// Depth-2 software pipeline (nl 2 ahead, S/E 1 ahead), pinned with
// sched_barrier(0) after each issue_se (R8 finding: hipcc sinks the prefetch
// otherwise, VGPR 52 proved pipeline collapse). 4 MFMAs/node -> G (bf16,RNE)
// -> ds_write_b64 into g_lds chunk (c + 16*(2lt + (q>>1))) ^ (node&7): 2-way
// write conflicts only (free). LDS 32 KB.
// Phase B: wave wid = m-tile; 32 K-steps x (ds_read_b128 + 16B wt + MFMA).
//
// R7 (FAILED): bounds (256,5): no occupancy change, spills. Reverted.
// R8 (WIN 68->59.6): sched_barrier pins. But VGPR=60 -> pipeline still only
// partially materialized; occupancy immovable at ~33% across all attempts.
// R9: phase A is VMEM-instruction/segment bound (168 instrs/wave, ~45K stall
// cycles/wave unexplainable by per-node latency). Free L-remap L=4c+lt turns
// the 32 strided S dword-loads/node into 8 dwordx4 row loads/node (72 VMEM
// instrs/wave total), zero cross-lane cost; k-enum + prep_wt permuted to
// match; phase B unchanged.
// ============================================================================
template <bool USE_WT>
__global__ __launch_bounds__(256, 3)
void mp_kernel(const float* __restrict__ nodes, const int* __restrict__ nlist,
               const float* __restrict__ edges, const unsigned short* __restrict__ wt,
               const float* __restrict__ w, float* __restrict__ out) {
  __shared__ u32 g_lds[16 * 512];   // 32 KB: G (bf16) in phase-B A-frag order

  const int tid = threadIdx.x;
  const int lane = tid & 63;
  const int wid = __builtin_amdgcn_readfirstlane(tid >> 6);
  const int q = lane >> 4, c = lane & 15;

  // XCD-aware mapping: batch b's 4 MB nodes slab pinned to 4 XCDs' L2.
  const int blk = blockIdx.x;
  const int xcd = blk & 7;
  const int batch = xcd >> 2;
  const int ordinal = ((blk >> 3) << 2) + (xcd & 3);    // [0,1024)
  const int wg0 = (batch << LOGN) + (ordinal << 4);
  const float* __restrict__ nbase = nodes + ((size_t)batch << 20);

  const int nd0 = wid << 2;                              // this wave's first node

  auto issue_nl = [&](int t, int4* ni) {
    const int* r = nlist + (((size_t)(wg0 + nd0 + t)) << 5) + (q << 3);
    ni[0] = *(const int4*)r;        // ix[q*8+0 .. +3]
    ni[1] = *(const int4*)(r + 4);  // ix[q*8+4 .. +7]
  };
  auto issue_se = [&](int t, const int4* ni, f32x4* R, float* E) {
    const int ix[8] = {ni[0].x, ni[0].y, ni[0].z, ni[0].w,
                       ni[1].x, ni[1].y, ni[1].z, ni[1].w};
    #pragma unroll
    for (int i = 0; i < 8; ++i)
      R[i] = *(const f32x4*)(nbase + ((size_t)(u32)ix[i] << 6) + (c << 2));
    const float* ep = edges + (((size_t)(wg0 + nd0 + t)) << 9) + (q << 7) + c;
    #pragma unroll
    for (int i = 0; i < 8; ++i) E[i] = ep[i << 4];
  };
  auto consume = [&](int p, const f32x4* R, const float* E) {
    uint4 apk{pkrne(E[0], E[1]), pkrne(E[2], E[3]),
              pkrne(E[4], E[5]), pkrne(E[6], E[7])};
    const bf16x8 af = __builtin_bit_cast(bf16x8, apk);
    #pragma unroll
    for (int lt = 0; lt < 4; ++lt) {
      // B-frag col c = L = 4c+lt -> element lt of each row's float4
      uint4 spk{pkrne(R[0][lt], R[1][lt]), pkrne(R[2][lt], R[3][lt]),
                pkrne(R[4][lt], R[5][lt]), pkrne(R[6][lt], R[7][lt])};
      f32x4 acc{0.f, 0.f, 0.f, 0.f};
      acc = __builtin_amdgcn_mfma_f32_16x16x32_bf16(af,
              __builtin_bit_cast(bf16x8, spk), acc, 0, 0, 0);
      // lane holds G^T[n=4q+r][L=4c+lt]; chunk = (c + 16*(2lt+(q>>1))) ^ (p&7)
      const u32 lo = pkrne(acc[0], acc[1]);
      const u32 hi = pkrne(acc[2], acc[3]);
      const int chunk = (c + (((lt << 1) + (q >> 1)) << 4)) ^ (p & 7);
      *(uint2*)&g_lds[(p << 9) + (chunk << 2) + ((q & 1) << 1)] = uint2{lo, hi};
    }
  };

  // ---------------- Phase A: pinned depth-2 pipeline ----------------
  // SFENCE() after each issue_se(t+1) forbids the compiler from sinking the
  // prefetch loads below the consume of the other buffer (the R0/R8 finding).
  {
    int4 ni0[2], ni1[2];
    f32x4 R0[8], R1[8];
    float E0[8], E1[8];
    issue_nl(0, ni0);
    issue_nl(1, ni1);
    issue_se(0, ni0, R0, E0);       // waits nl(0) only; nl(1) stays in flight
    issue_nl(2, ni0);
    issue_se(1, ni1, R1, E1);       // waits nl(1); SE(0)+nl(2) in flight
    issue_nl(3, ni1);
    SFENCE();                       // SE(0)+SE(1) pinned above consume(0)
    consume(nd0 + 0, R0, E0);       // waits SE(0); SE(1)+nl(3) in flight
    issue_se(2, ni0, R0, E0);
    SFENCE();                       // SE(2) pinned above consume(1)
    consume(nd0 + 1, R1, E1);
    issue_se(3, ni1, R1, E1);
    SFENCE();                       // SE(3) pinned above consume(2)
    consume(nd0 + 2, R0, E0);
    consume(nd0 + 3, R1, E1);
  }

  LGKM0();      // G writes visible
  BARRIER();

  // ---------------- Phase B: out[node][m] = sum_k G2[node][k] * wt[m][k] ----
  // A-frag: lane(q,c): G2[node=c][k=32s+8q+i] -> chunk 4s+q (^c&7), b128.
  const int m = (wid << 4) + c;
  f32x4 ob{0.f, 0.f, 0.f, 0.f};
  if (USE_WT) {
    const unsigned short* wb = wt + ((size_t)m << 10) + (q << 3);
    #pragma unroll 8
    for (int s = 0; s < 32; ++s) {
      uint4 ar = *(const uint4*)&g_lds[(c << 9) + ((((s << 2) + q) ^ (c & 7)) << 2)];
      ob = __builtin_amdgcn_mfma_f32_16x16x32_bf16(__builtin_bit_cast(bf16x8, ar),
                                                   *(const bf16x8*)(wb + (s << 5)),
                                                   ob, 0, 0, 0);
    }
  } else {
    #pragma unroll 4
    for (int s = 0; s < 32; ++s) {
      uint4 ar = *(const uint4*)&g_lds[(c << 9) + ((((s << 2) + q) ^ (c & 7)) << 2)];
      // k = 32s+8q+i: ch = 4s+q -> L = 4*(ch&15) + (ch>>5), n0 = ((ch>>4)&1)*8
      const int ch = (s << 2) + q;
      const int l = ((ch & 15) << 2) + (ch >> 5);
      const int n0 = ((ch >> 4) & 1) << 3;
      const float* wp = w + l * 1024 + m * 16 + n0;
      ob = __builtin_amdgcn_mfma_f32_16x16x32_bf16(__builtin_bit_cast(bf16x8, ar),
                                                   mk_bw(wp), ob, 0, 0, 0);
    }
  }

  // D: lane(q,c): out[node = 4q+r][mfeat = m]
  #pragma unroll
  for (int r = 0; r < 4; ++r)
    out[((size_t)(wg0 + (q << 2) + r) << 6) + m] = ob[r];
}

extern "C" void kernel_launch(void* const* d_in, const int* in_sizes, int n_in,
                              void* d_out, int out_size, void* d_ws, size_t ws_size,
                              hipStream_t stream) {
  const float* nodes = (const float*)d_in[0];
  const int*   nlist = (const int*)d_in[1];
  const float* edges = (const float*)d_in[2];
  const float* w     = (const float*)d_in[3];
  float* out = (float*)d_out;

  if (ws_size >= 131072) {
    unsigned short* wt = (unsigned short*)d_ws;
    prep_wt<<<256, 256, 0, stream>>>(w, wt);
    mp_kernel<true><<<2048, 256, 0, stream>>>(nodes, nlist, edges, wt, w, out);
  } else {
    mp_kernel<false><<<2048, 256, 0, stream>>>(nodes, nlist, edges, nullptr, w, out);
  }
}

// Round 4
// 144.092 us; speedup vs baseline: 1.0275x; 1.0275x over previous
//
#include <hip/hip_runtime.h>
#include <cstdint>
#include <cstddef>

// Problem constants: B=2, N=16384, K=32, F=64, E=16
#define LOGN 14

typedef __bf16 bf16x8 __attribute__((ext_vector_type(8)));
typedef float f32x4 __attribute__((ext_vector_type(4)));
typedef unsigned u32;

// raw barrier + lgkmcnt(0)-only wait (vmcnt/expcnt unconstrained: 0xC07F)
#define BARRIER() __builtin_amdgcn_s_barrier()
#define LGKM0()   __builtin_amdgcn_s_waitcnt(0xC07F)
// full scheduling fence: nothing moves across (pins the SW pipeline)
#define SFENCE()  __builtin_amdgcn_sched_barrier(0)

__device__ __forceinline__ u32 fbits(float f) { return __builtin_bit_cast(u32, f); }
// pack two f32 -> dword of 2 bf16 (RNE), lo -> low16
__device__ __forceinline__ u32 pkrne(float lo, float hi) {
  u32 a = fbits(lo); a = a + 0x7fffu + ((a >> 16) & 1u);
  u32 b = fbits(hi); b = b + 0x7fffu + ((b >> 16) & 1u);
  return (b & 0xffff0000u) | (a >> 16);
}

// ----------------------------------------------------------------------------
// k-enumeration (R9): k in [0,1024) <-> (L,n) via chunk ch = k>>3, wv = k&7:
//   t = ch>>4, c = ch&15, L = 4*c + (t>>1), n = 8*(t&1) + wv.
// B-frag S value for (lane c, l-tile lt) = S_row[4c+lt] -> contiguous 4-elem
// group per lane; with the bf16 node table each lane reads 8B (dwordx2).
// ----------------------------------------------------------------------------

// wt[m][k] = w[L(k)][m][n(k)]/32 (bf16), 64x1024 = 128KB
__global__ void prep_wt(const float* __restrict__ w, unsigned short* __restrict__ wt) {
  int idx = blockIdx.x * 256 + threadIdx.x;
  int m = idx >> 10, k = idx & 1023;
  int ch = k >> 3, wv = k & 7, t = ch >> 4, cc = ch & 15;
  int l = (cc << 2) + (t >> 1), n = ((t & 1) << 3) + wv;
  u32 u = fbits(w[l * 1024 + m * 16 + n] * 0.03125f);
  wt[idx] = (unsigned short)((u + 0x7fffu + ((u >> 16) & 1u)) >> 16);
}

// nb[row][l] = bf16(nodes[row][l]), RNE — identical bits to the old in-kernel
// pkrne conversion, just hoisted. 2*16384*64 = 2M elems; 8 per thread.
__global__ void prep_nb(const float* __restrict__ nodes, unsigned short* __restrict__ nb) {
  int idx = blockIdx.x * 256 + threadIdx.x;       // 262144 threads
  const float4* p = (const float4*)nodes + ((size_t)idx << 1);
  float4 a = p[0], b = p[1];
  uint4 o{pkrne(a.x, a.y), pkrne(a.z, a.w), pkrne(b.x, b.y), pkrne(b.z, b.w)};
  *((uint4*)nb + idx) = o;
}

__device__ __forceinline__ bf16x8 mk_bw(const float* wp) {
  float v[8];
  #pragma unroll
  for (int i = 0; i < 8; ++i) v[i] = wp[i] * 0.03125f;
  uint4 pk{pkrne(v[0], v[1]), pkrne(v[2], v[3]), pkrne(v[4], v[5]), pkrne(v[6], v[7])};
  return __builtin_bit_cast(bf16x8, pk);
}

// ============================================================================
// WG = 256 threads (4 waves) = 16 nodes; wave wid owns nodes wid*4..wid*4+3.
// Phase A: fragments gathered directly from global, depth-2 pipeline pinned
// with sched_barrier(0) (R8: -12%). Phase B: wave wid = m-tile; 32 K-steps x
// (ds_read_b128 + 16B wt load + MFMA); wt L2-resident.
//
// R7 (FAILED): bounds (256,5): no occupancy change, spills. Reverted.
// R8 (WIN 68->59.6): sched_barrier pins the prefetch.
// R9 (NEUTRAL 59.6->58.9): S loads dword->dwordx4 (4x fewer VMEM instrs).
//   Null with LINE COUNT held constant => bottleneck is cache-line transaction
//   throughput (TA/L1), not instruction issue: ~4.7K lines/WG (2048 S + 2048
//   wt + 512 E) * 8 WG/CU ~ 38K lines/CU ~ the observed 59us with all pipes
//   <25% busy.
// R10 (this): pre-convert nodes to a bf16 table (prep_nb, 4MB ws). S rows:
//   256B -> 128B = 2 lines/row, S lines 2048->1024/WG (-22% total). B-frag
//   repack becomes 16 v_perm_b32/node (was 16 pkrne ~7 VALU each); per-buffer
//   state 32->16 VGPRs. Numerics bit-identical (same RNE, hoisted).
//   MODE: 2 = wt + bf16-nodes, 1 = wt only (R9 path), 0 = no workspace.
// ============================================================================
template <int MODE>
__global__ __launch_bounds__(256, 3)
void mp_kernel(const float* __restrict__ nodes, const int* __restrict__ nlist,
               const float* __restrict__ edges, const unsigned short* __restrict__ wt,
               const unsigned short* __restrict__ nb,
               const float* __restrict__ w, float* __restrict__ out) {
  __shared__ u32 g_lds[16 * 512];   // 32 KB: G (bf16) in phase-B A-frag order

  const int tid = threadIdx.x;
  const int lane = tid & 63;
  const int wid = __builtin_amdgcn_readfirstlane(tid >> 6);
  const int q = lane >> 4, c = lane & 15;

  // XCD-aware mapping: batch b's nodes slab pinned to 4 XCDs' L2.
  const int blk = blockIdx.x;
  const int xcd = blk & 7;
  const int batch = xcd >> 2;
  const int ordinal = ((blk >> 3) << 2) + (xcd & 3);    // [0,1024)
  const int wg0 = (batch << LOGN) + (ordinal << 4);
  const float* __restrict__ nbase = nodes + ((size_t)batch << 20);
  const unsigned short* __restrict__ nbb = nb + ((size_t)batch << 20);

  const int nd0 = wid << 2;                              // this wave's first node

  auto issue_nl = [&](int t, int4* ni) {
    const int* r = nlist + (((size_t)(wg0 + nd0 + t)) << 5) + (q << 3);
    ni[0] = *(const int4*)r;        // ix[q*8+0 .. +3]
    ni[1] = *(const int4*)(r + 4);  // ix[q*8+4 .. +7]
  };
  auto issue_se = [&](int t, const int4* ni, f32x4* R, uint2* U, float* E) {
    const int ix[8] = {ni[0].x, ni[0].y, ni[0].z, ni[0].w,
                       ni[1].x, ni[1].y, ni[1].z, ni[1].w};
    if constexpr (MODE == 2) {
      #pragma unroll
      for (int i = 0; i < 8; ++i)
        U[i] = *(const uint2*)(nbb + ((size_t)(u32)ix[i] << 6) + (c << 2));
    } else {
      #pragma unroll
      for (int i = 0; i < 8; ++i)
        R[i] = *(const f32x4*)(nbase + ((size_t)(u32)ix[i] << 6) + (c << 2));
    }
    const float* ep = edges + (((size_t)(wg0 + nd0 + t)) << 9) + (q << 7) + c;
    #pragma unroll
    for (int i = 0; i < 8; ++i) E[i] = ep[i << 4];
  };
  auto consume = [&](int p, const f32x4* R, const uint2* U, const float* E) {
    uint4 apk{pkrne(E[0], E[1]), pkrne(E[2], E[3]),
              pkrne(E[4], E[5]), pkrne(E[6], E[7])};
    const bf16x8 af = __builtin_bit_cast(bf16x8, apk);
    #pragma unroll
    for (int lt = 0; lt < 4; ++lt) {
      uint4 spk;
      if constexpr (MODE == 2) {
        // bf16 row data: U[i] = {L=4c+0,4c+1 | L=4c+2,4c+3}. Tile lt picks one
        // bf16 per row; dword d = rows {2d(lo16), 2d+1(hi16)} via v_perm_b32.
        const u32 sel = (lt & 1) ? 0x07060302u : 0x05040100u;
        u32 p0, p1, p2, p3;
        if (lt & 2) {
          p0 = __builtin_amdgcn_perm(U[1].y, U[0].y, sel);
          p1 = __builtin_amdgcn_perm(U[3].y, U[2].y, sel);
          p2 = __builtin_amdgcn_perm(U[5].y, U[4].y, sel);
          p3 = __builtin_amdgcn_perm(U[7].y, U[6].y, sel);
        } else {
          p0 = __builtin_amdgcn_perm(U[1].x, U[0].x, sel);
          p1 = __builtin_amdgcn_perm(U[3].x, U[2].x, sel);
          p2 = __builtin_amdgcn_perm(U[5].x, U[4].x, sel);
          p3 = __builtin_amdgcn_perm(U[7].x, U[6].x, sel);
        }
        spk = uint4{p0, p1, p2, p3};
      } else {
        spk = uint4{pkrne(R[0][lt], R[1][lt]), pkrne(R[2][lt], R[3][lt]),
                    pkrne(R[4][lt], R[5][lt]), pkrne(R[6][lt], R[7][lt])};
      }
      f32x4 acc{0.f, 0.f, 0.f, 0.f};
      acc = __builtin_amdgcn_mfma_f32_16x16x32_bf16(af,
              __builtin_bit_cast(bf16x8, spk), acc, 0, 0, 0);
      // lane holds G^T[n=4q+r][L=4c+lt]; chunk = (c + 16*(2lt+(q>>1))) ^ (p&7)
      const u32 lo = pkrne(acc[0], acc[1]);
      const u32 hi = pkrne(acc[2], acc[3]);
      const int chunk = (c + (((lt << 1) + (q >> 1)) << 4)) ^ (p & 7);
      *(uint2*)&g_lds[(p << 9) + (chunk << 2) + ((q & 1) << 1)] = uint2{lo, hi};
    }
  };

  // ---------------- Phase A: pinned depth-2 pipeline ----------------
  {
    int4 ni0[2], ni1[2];
    f32x4 R0[8], R1[8];
    uint2 U0[8], U1[8];
    float E0[8], E1[8];
    issue_nl(0, ni0);
    issue_nl(1, ni1);
    issue_se(0, ni0, R0, U0, E0);   // waits nl(0) only; nl(1) stays in flight
    issue_nl(2, ni0);
    issue_se(1, ni1, R1, U1, E1);   // waits nl(1); SE(0)+nl(2) in flight
    issue_nl(3, ni1);
    SFENCE();                       // SE(0)+SE(1) pinned above consume(0)
    consume(nd0 + 0, R0, U0, E0);   // waits SE(0); SE(1)+nl(3) in flight
    issue_se(2, ni0, R0, U0, E0);
    SFENCE();                       // SE(2) pinned above consume(1)
    consume(nd0 + 1, R1, U1, E1);
    issue_se(3, ni1, R1, U1, E1);
    SFENCE();                       // SE(3) pinned above consume(2)
    consume(nd0 + 2, R0, U0, E0);
    consume(nd0 + 3, R1, U1, E1);
  }

  LGKM0();      // G writes visible
  BARRIER();

  // ---------------- Phase B: out[node][m] = sum_k G2[node][k] * wt[m][k] ----
  // A-frag: lane(q,c): G2[node=c][k=32s+8q+i] -> chunk 4s+q (^c&7), b128.
  const int m = (wid << 4) + c;
  f32x4 ob{0.f, 0.f, 0.f, 0.f};
  if constexpr (MODE >= 1) {
    const unsigned short* wb = wt + ((size_t)m << 10) + (q << 3);
    #pragma unroll 8
    for (int s = 0; s < 32; ++s) {
      uint4 ar = *(const uint4*)&g_lds[(c << 9) + ((((s << 2) + q) ^ (c & 7)) << 2)];
      ob = __builtin_amdgcn_mfma_f32_16x16x32_bf16(__builtin_bit_cast(bf16x8, ar),
                                                   *(const bf16x8*)(wb + (s << 5)),
                                                   ob, 0, 0, 0);
    }
  } else {
    #pragma unroll 4
    for (int s = 0; s < 32; ++s) {
      uint4 ar = *(const uint4*)&g_lds[(c << 9) + ((((s << 2) + q) ^ (c & 7)) << 2)];
      // k = 32s+8q+i: ch = 4s+q -> L = 4*(ch&15) + (ch>>5), n0 = ((ch>>4)&1)*8
      const int ch = (s << 2) + q;
      const int l = ((ch & 15) << 2) + (ch >> 5);
      const int n0 = ((ch >> 4) & 1) << 3;
      const float* wp = w + l * 1024 + m * 16 + n0;
      ob = __builtin_amdgcn_mfma_f32_16x16x32_bf16(__builtin_bit_cast(bf16x8, ar),
                                                   mk_bw(wp), ob, 0, 0, 0);
    }
  }

  // D: lane(q,c): out[node = 4q+r][mfeat = m]
  #pragma unroll
  for (int r = 0; r < 4; ++r)
    out[((size_t)(wg0 + (q << 2) + r) << 6) + m] = ob[r];
}

extern "C" void kernel_launch(void* const* d_in, const int* in_sizes, int n_in,
                              void* d_out, int out_size, void* d_ws, size_t ws_size,
                              hipStream_t stream) {
  const float* nodes = (const float*)d_in[0];
  const int*   nlist = (const int*)d_in[1];
  const float* edges = (const float*)d_in[2];
  const float* w     = (const float*)d_in[3];
  float* out = (float*)d_out;

  const size_t WT_BYTES = 131072;               // 64x1024 bf16
  const size_t NB_BYTES = (size_t)1 << 22;      // 2x16384x64 bf16 = 4 MB

  if (ws_size >= WT_BYTES + NB_BYTES) {
    unsigned short* wt = (unsigned short*)d_ws;
    unsigned short* nb = wt + 65536;            // after the 128KB wt table
    prep_wt<<<256, 256, 0, stream>>>(w, wt);
    prep_nb<<<1024, 256, 0, stream>>>(nodes, nb);
    mp_kernel<2><<<2048, 256, 0, stream>>>(nodes, nlist, edges, wt, nb, w, out);
  } else if (ws_size >= WT_BYTES) {
    unsigned short* wt = (unsigned short*)d_ws;
    prep_wt<<<256, 256, 0, stream>>>(w, wt);
    mp_kernel<1><<<2048, 256, 0, stream>>>(nodes, nlist, edges, wt, nullptr, w, out);
  } else {
    mp_kernel<0><<<2048, 256, 0, stream>>>(nodes, nlist, edges, nullptr, nullptr, w, out);
  }
}